// Round 13
// baseline (14234.868 us; speedup 1.0000x reference)
//
#include <hip/hip_runtime.h>
#include <math.h>

namespace {
constexpr int   Bb    = 16;
constexpr int   Nn    = 2048;
constexpr int   Mm    = 2048;
constexpr float EPSf  = 0.005f;
constexpr float TOLf  = 1e-3f;
constexpr int   MAXIT = 100;
constexpr float LN2f  = 0.69314718055994531f;
constexpr float L2Ef  = 1.44269504088896340f;  // log2(e)
constexpr float C2f   = 288.53900817779268f;   // log2(e)/EPS
constexpr int   BLOCK = 256;                   // helper kernels
constexpr int   BLK   = 1024;                  // persistent kernel block
constexpr int   PGRID = 256;                   // persistent grid: 16 blocks/batch
constexpr int   NCH   = 32;                    // 64-pt chunks per batch
constexpr int   SLOTSTRIDE = 16;               // dwords per (it,batch) slot line
}

__device__ __forceinline__ float ex2(float x) { return __builtin_amdgcn_exp2f(x); }

__global__ __launch_bounds__(BLOCK) void pack_pts(const float* __restrict__ p,
                                                  float4* __restrict__ pk, int npts) {
  int i = blockIdx.x * BLOCK + threadIdx.x;
  if (i < npts) pk[i] = make_float4(p[3 * i], p[3 * i + 1], p[3 * i + 2], 0.0f);
}

__global__ void init_bar(unsigned* cnt, unsigned* gen) {
  *cnt = 0u; *gen = 0u;
}

// per-(cloud,batch) bounding box
__global__ __launch_bounds__(BLOCK) void bbox_k(const float4* __restrict__ pk1,
                                                const float4* __restrict__ pk2,
                                                float4* __restrict__ bbox) {
  __shared__ float4 smin[BLOCK], smax[BLOCK];
  const int cb = blockIdx.x;
  const float4* p = (cb < 16 ? pk1 : pk2) + (cb & 15) * Nn;
  float4 mn = make_float4(3e38f, 3e38f, 3e38f, 0), mx = make_float4(-3e38f, -3e38f, -3e38f, 0);
  for (int i = threadIdx.x; i < Nn; i += BLOCK) {
    float4 v = p[i];
    mn.x = fminf(mn.x, v.x); mn.y = fminf(mn.y, v.y); mn.z = fminf(mn.z, v.z);
    mx.x = fmaxf(mx.x, v.x); mx.y = fmaxf(mx.y, v.y); mx.z = fmaxf(mx.z, v.z);
  }
  smin[threadIdx.x] = mn; smax[threadIdx.x] = mx;
  __syncthreads();
  for (int k = BLOCK / 2; k > 0; k >>= 1) {
    if (threadIdx.x < k) {
      float4 a = smin[threadIdx.x], c = smin[threadIdx.x + k];
      smin[threadIdx.x] = make_float4(fminf(a.x, c.x), fminf(a.y, c.y), fminf(a.z, c.z), 0);
      float4 d = smax[threadIdx.x], e = smax[threadIdx.x + k];
      smax[threadIdx.x] = make_float4(fmaxf(d.x, e.x), fmaxf(d.y, e.y), fmaxf(d.z, e.z), 0);
    }
    __syncthreads();
  }
  if (threadIdx.x == 0) { bbox[cb * 2] = smin[0]; bbox[cb * 2 + 1] = smax[0]; }
}

__device__ __forceinline__ unsigned spread3(unsigned v) {
  v = (v * 0x00010001u) & 0xFF0000FFu;
  v = (v * 0x00000101u) & 0x0F00F00Fu;
  v = (v * 0x00000011u) & 0xC30C30C3u;
  v = (v * 0x00000005u) & 0x49249249u;
  return v;
}

// Morton-sort one (cloud,batch) in LDS; affects pruning speed only, not correctness.
__global__ __launch_bounds__(BLOCK) void sort_k(float4* __restrict__ pk1,
                                                float4* __restrict__ pk2,
                                                const float4* __restrict__ bbox,
                                                float4* __restrict__ chunkbox) {
  __shared__ float4 pts[Nn];                    // 32 KB
  __shared__ unsigned key[Nn];                  // 8 KB
  const int cb = blockIdx.x, tid = threadIdx.x;
  float4* p = (cb < 16 ? pk1 : pk2) + (cb & 15) * Nn;
  float4 lo = bbox[cb * 2], hi = bbox[cb * 2 + 1];
  float sx = 127.0f / fmaxf(hi.x - lo.x, 1e-9f);
  float sy = 127.0f / fmaxf(hi.y - lo.y, 1e-9f);
  float sz = 127.0f / fmaxf(hi.z - lo.z, 1e-9f);
  for (int i = tid; i < Nn; i += BLOCK) {
    float4 v = p[i];
    pts[i] = v;
    unsigned qx = (unsigned)fminf(fmaxf((v.x - lo.x) * sx, 0.f), 127.f);
    unsigned qy = (unsigned)fminf(fmaxf((v.y - lo.y) * sy, 0.f), 127.f);
    unsigned qz = (unsigned)fminf(fmaxf((v.z - lo.z) * sz, 0.f), 127.f);
    unsigned m = spread3(qx) | (spread3(qy) << 1) | (spread3(qz) << 2);
    key[i] = (m << 11) | (unsigned)i;
  }
  __syncthreads();
  for (int k = 2; k <= Nn; k <<= 1)
    for (int j = k >> 1; j > 0; j >>= 1) {
      for (int t = tid; t < Nn / 2; t += BLOCK) {
        int i = ((t & ~(j - 1)) << 1) | (t & (j - 1));
        int ixj = i | j;
        bool up = ((i & k) == 0);
        unsigned a = key[i], bq = key[ixj];
        if ((a > bq) == up) { key[i] = bq; key[ixj] = a; }
      }
      __syncthreads();
    }
  float4 g[Nn / BLOCK];
  #pragma unroll
  for (int c = 0; c < Nn / BLOCK; ++c)
    g[c] = pts[key[tid + c * BLOCK] & 2047u];
  __syncthreads();
  #pragma unroll
  for (int c = 0; c < Nn / BLOCK; ++c) {
    pts[tid + c * BLOCK] = g[c];
    p[tid + c * BLOCK]   = g[c];
  }
  __syncthreads();
  const int lane = tid & 63, wid = tid >> 6;
  for (int c = wid; c < NCH; c += 4) {
    float4 v = pts[c * 64 + lane];
    float mnx = v.x, mny = v.y, mnz = v.z, mxx = v.x, mxy = v.y, mxz = v.z;
    #pragma unroll
    for (int off = 1; off < 64; off <<= 1) {
      mnx = fminf(mnx, __shfl_xor(mnx, off)); mny = fminf(mny, __shfl_xor(mny, off));
      mnz = fminf(mnz, __shfl_xor(mnz, off)); mxx = fmaxf(mxx, __shfl_xor(mxx, off));
      mxy = fmaxf(mxy, __shfl_xor(mxy, off)); mxz = fmaxf(mxz, __shfl_xor(mxz, off));
    }
    if (lane == 0) {
      chunkbox[(cb * NCH + c) * 2]     = make_float4(mnx, mny, mnz, 0);
      chunkbox[(cb * NCH + c) * 2 + 1] = make_float4(mxx, mxy, mxz, 0);
    }
  }
}

// sense-reversing grid barrier with agent-scope release/acquire.
// Safe: launch_bounds(1024,8) => VGPR<=64 => >=2 blocks/CU capacity;
// PGRID=256 <= 256 CUs * 2 => all blocks co-resident => no deadlock.
__device__ __forceinline__ void gbar(unsigned* cnt, unsigned* gen) {
  __syncthreads();
  if (threadIdx.x == 0) {
    __builtin_amdgcn_fence(__ATOMIC_RELEASE, "agent");
    unsigned g = __hip_atomic_load(gen, __ATOMIC_RELAXED, __HIP_MEMORY_SCOPE_AGENT);
    unsigned a = __hip_atomic_fetch_add(cnt, 1u, __ATOMIC_ACQ_REL, __HIP_MEMORY_SCOPE_AGENT);
    if (a == (unsigned)(PGRID - 1)) {
      __hip_atomic_store(cnt, 0u, __ATOMIC_RELAXED, __HIP_MEMORY_SCOPE_AGENT);
      __hip_atomic_store(gen, g + 1u, __ATOMIC_RELEASE, __HIP_MEMORY_SCOPE_AGENT);
    } else {
      while (__hip_atomic_load(gen, __ATOMIC_RELAXED, __HIP_MEMORY_SCOPE_AGENT) == g)
        __builtin_amdgcn_s_sleep(2);
    }
    __builtin_amdgcn_fence(__ATOMIC_ACQUIRE, "agent");
  }
  __syncthreads();
}

// One half-pass for this block's 128 rows (2 groups of 4 rows per wave).
// FULL: online-max LSE (it=0). else: fixed-shift LSE + AABB chunk pruning.
template<bool FULL>
__device__ __forceinline__ void half_pass(
    const float4* __restrict__ PC, float4* __restrict__ PRq,
    float* __restrict__ QR,
    const float4* __restrict__ cboxC, const float* __restrict__ cmC,
    float* __restrict__ cmO, unsigned* slot,
    int sl, int lane, int wid, int tid, float thrAdd,
    float* red, float* redw) {
  const float log_ab = logf(1.0f / 2048.0f + 1e-8f);
  const float log2ab = log_ab * L2Ef;
  const float invC2  = 1.0f / C2f;

  float4 clo = make_float4(0, 0, 0, 0), chi = clo;
  float cmw = -3.0e38f;
  if (!FULL && lane < 32) {
    clo = cboxC[lane * 2]; chi = cboxC[lane * 2 + 1]; cmw = cmC[lane];
  }

  float dmax = 0.0f, wchunk = -3.0e38f;
  float* PRw = (float*)PRq;
  #pragma unroll
  for (int g = 0; g < 2; ++g) {
    const int base = sl * 128 + wid * 8 + g * 4;
    float qx[4], qy[4], qz[4], A[4], S[4], up[4];
    #pragma unroll
    for (int r = 0; r < 4; ++r) {
      float4 q = PRq[base + r];                 // wave-uniform
      qx[r] = q.x; qy[r] = q.y; qz[r] = q.z;
      up[r] = QR[base + r];
      A[r] = FULL ? -3.0e38f : (log2ab - q.w);
      S[r] = 0.0f;
    }
    const float4* p = PC + lane;

    if (FULL) {
      #pragma unroll 2
      for (int j = 0; j < 32; j += 4) {
        float4 f0 = p[(j + 0) * 64];
        float4 f1 = p[(j + 1) * 64];
        float4 f2 = p[(j + 2) * 64];
        float4 f3 = p[(j + 3) * 64];
        #pragma unroll
        for (int r = 0; r < 4; ++r) {
          float dx0 = f0.x - qx[r], dy0 = f0.y - qy[r], dz0 = f0.z - qz[r];
          float dx1 = f1.x - qx[r], dy1 = f1.y - qy[r], dz1 = f1.z - qz[r];
          float dx2 = f2.x - qx[r], dy2 = f2.y - qy[r], dz2 = f2.z - qz[r];
          float dx3 = f3.x - qx[r], dy3 = f3.y - qy[r], dz3 = f3.z - qz[r];
          float d0 = fmaf(dz0, dz0, fmaf(dy0, dy0, dx0 * dx0));
          float d1 = fmaf(dz1, dz1, fmaf(dy1, dy1, dx1 * dx1));
          float d2 = fmaf(dz2, dz2, fmaf(dy2, dy2, dx2 * dx2));
          float d3 = fmaf(dz3, dz3, fmaf(dy3, dy3, dx3 * dx3));
          float y0 = fmaf(__builtin_amdgcn_sqrtf(d0), -C2f, f0.w);
          float y1 = fmaf(__builtin_amdgcn_sqrtf(d1), -C2f, f1.w);
          float y2 = fmaf(__builtin_amdgcn_sqrtf(d2), -C2f, f2.w);
          float y3 = fmaf(__builtin_amdgcn_sqrtf(d3), -C2f, f3.w);
          float pm = fmaxf(fmaxf(y0, y1), fmaxf(y2, y3));
          float nm = fmaxf(A[r], pm);
          float e  = (ex2(y0 - nm) + ex2(y1 - nm)) + (ex2(y2 - nm) + ex2(y3 - nm));
          S[r] = fmaf(S[r], ex2(A[r] - nm), e);
          A[r] = nm;
        }
      }
    } else {
      unsigned msk = 0;
      #pragma unroll
      for (int r = 0; r < 4; ++r) {
        float thr = (cmw - A[r] + thrAdd) * invC2;
        float ax = fmaxf(fmaxf(clo.x - qx[r], qx[r] - chi.x), 0.0f);
        float ay = fmaxf(fmaxf(clo.y - qy[r], qy[r] - chi.y), 0.0f);
        float az = fmaxf(fmaxf(clo.z - qz[r], qz[r] - chi.z), 0.0f);
        float d2low = fmaf(az, az, fmaf(ay, ay, ax * ax));
        bool keep = (lane < 32) && (thr > 0.0f) && (d2low <= thr * thr);
        msk |= (unsigned)(__ballot(keep) & 0xFFFFFFFFull);
      }
      if (msk) {
        int j = __builtin_ctz(msk); msk &= msk - 1;
        float4 f = p[j * 64];
        for (;;) {
          float4 fn; bool more = (msk != 0);
          if (more) { int jn = __builtin_ctz(msk); msk &= msk - 1; fn = p[jn * 64]; }
          #pragma unroll
          for (int r = 0; r < 4; ++r) {
            float dx = f.x - qx[r], dy = f.y - qy[r], dz = f.z - qz[r];
            float d2 = fmaf(dz, dz, fmaf(dy, dy, dx * dx));
            S[r] += ex2(fmaf(__builtin_amdgcn_sqrtf(d2), -C2f, f.w - A[r]));
          }
          if (!more) break;
          f = fn;
        }
      }
    }

    #pragma unroll
    for (int r = 0; r < 4; ++r) {
      float pnew;
      if (FULL) {
        float gm = A[r];
        #pragma unroll
        for (int off = 1; off < 64; off <<= 1) gm = fmaxf(gm, __shfl_xor(gm, off));
        float sc = S[r] * ex2(A[r] - gm);
        #pragma unroll
        for (int off = 1; off < 64; off <<= 1) sc += __shfl_xor(sc, off);
        float lse = (gm + __builtin_amdgcn_logf(sc)) * LN2f;
        pnew = EPSf * (log_ab - lse);
      } else {
        float sv = S[r];
        #pragma unroll
        for (int off = 1; off < 64; off <<= 1) sv += __shfl_xor(sv, off);
        sv = fmaxf(sv, 1e-37f);
        float lse = (A[r] + __builtin_amdgcn_logf(sv)) * LN2f;
        pnew = EPSf * (log_ab - lse);
      }
      if (lane == 0) {
        int n = base + r;
        dmax = fmaxf(dmax, fabsf(pnew - up[r]));
        QR[n] = pnew;
        PRw[4 * n + 3] = pnew * C2f;
        wchunk = fmaxf(wchunk, pnew * C2f);
      }
    }
  }
  if (lane == 0) { red[wid] = dmax; redw[wid] = wchunk; }
  __syncthreads();
  if (tid == 0) {
    float m = red[0];
    #pragma unroll
    for (int i = 1; i < 16; ++i) m = fmaxf(m, red[i]);
    atomicMax(slot, __float_as_uint(m));
    float w0 = redw[0], w1 = redw[8];
    #pragma unroll
    for (int i = 1; i < 8; ++i) { w0 = fmaxf(w0, redw[i]); w1 = fmaxf(w1, redw[8 + i]); }
    cmO[sl * 2] = w0;
    cmO[sl * 2 + 1] = w1;
  }
  __syncthreads();
}

// THE persistent kernel: init, 100 Sinkhorn iterations with grid barriers,
// uniform early break, final contraction, single reduce. Zero dispatch gaps.
__global__ __launch_bounds__(BLK, 8) void sink_all(
    float4* __restrict__ pk1, float4* __restrict__ pk2,
    float* __restrict__ U, float* __restrict__ V,
    unsigned* __restrict__ slots, const float4* __restrict__ cbox,
    float* __restrict__ cm, float* __restrict__ part, float* __restrict__ out,
    unsigned* cnt, unsigned* gen) {
  __shared__ float red[16], redw[16];
  __shared__ float convm;
  __shared__ double sd[256];
  const int bid = blockIdx.x, tid = threadIdx.x, lane = tid & 63, wid = tid >> 6;
  const int b = bid >> 4, sl = bid & 15;

  // prologue: zero this block's slices (replay-safe)
  if (tid < 128) {
    U[b * Nn + sl * 128 + tid] = 0.0f;
    V[b * Nn + sl * 128 + tid] = 0.0f;
  }
  if (tid < 100) slots[bid * 100 + tid] = 0u;   // 256*100 = 25600 = MAXIT*Bb*16
  gbar(cnt, gen);

  const float4* cbox1 = cbox + (b)      * NCH * 2;
  const float4* cbox2 = cbox + (16 + b) * NCH * 2;
  float* cm1 = cm + b * NCH;
  float* cm2 = cm + 16 * NCH + b * NCH;
  float4* PK1 = pk1 + b * Nn;
  float4* PK2 = pk2 + b * Nn;
  float*  Ub  = U + b * Nn;
  float*  Vb  = V + b * Nn;

  for (int it = 0; it < MAXIT; ++it) {
    unsigned* su = slots + it * Bb * SLOTSTRIDE + b * SLOTSTRIDE + 0;
    unsigned* sv = slots + it * Bb * SLOTSTRIDE + b * SLOTSTRIDE + 1;
    float thr = (it < 4) ? 120.0f : 80.0f;
    if (it == 0) half_pass<true >(PK2, PK1, Ub, cbox2, cm2, cm1, su, sl, lane, wid, tid, thr, red, redw);
    else         half_pass<false>(PK2, PK1, Ub, cbox2, cm2, cm1, su, sl, lane, wid, tid, thr, red, redw);
    gbar(cnt, gen);
    if (it == 0) half_pass<true >(PK1, PK2, Vb, cbox1, cm1, cm2, sv, sl, lane, wid, tid, thr, red, redw);
    else         half_pass<false>(PK1, PK2, Vb, cbox1, cm1, cm2, sv, sl, lane, wid, tid, thr, red, redw);
    gbar(cnt, gen);
    // uniform convergence check: all blocks read identical dwords
    if (tid < 32) {
      float v = __uint_as_float(__hip_atomic_load(
          slots + it * Bb * SLOTSTRIDE + (tid >> 1) * SLOTSTRIDE + (tid & 1),
          __ATOMIC_RELAXED, __HIP_MEMORY_SCOPE_AGENT));
      #pragma unroll
      for (int off = 16; off >= 1; off >>= 1) v = fmaxf(v, __shfl_xor(v, off));
      if (tid == 0) convm = v;
    }
    __syncthreads();
    if (convm < TOLf) break;                    // uniform across grid
  }

  // final contraction: sum exp((u+v-dist)/eps)*dist over this block's rows
  float acc = 0.0f;
  #pragma unroll
  for (int g = 0; g < 2; ++g) {
    const int base = sl * 128 + wid * 8 + g * 4;
    float qx[4], qy[4], qz[4], uc[4];
    #pragma unroll
    for (int r = 0; r < 4; ++r) {
      float4 q = PK1[base + r];
      qx[r] = q.x; qy[r] = q.y; qz[r] = q.z;
      uc[r] = Ub[base + r] * C2f;
    }
    const float4* p = PK2 + lane;
    #pragma unroll 2
    for (int j = 0; j < 32; ++j) {
      float4 f = p[j * 64];
      #pragma unroll
      for (int r = 0; r < 4; ++r) {
        float dx = f.x - qx[r], dy = f.y - qy[r], dz = f.z - qz[r];
        float d2 = fmaf(dz, dz, fmaf(dy, dy, dx * dx));
        float t  = __builtin_amdgcn_sqrtf(d2);
        acc = fmaf(ex2(fmaf(t, -C2f, f.w) + uc[r]), t, acc);
      }
    }
  }
  #pragma unroll
  for (int off = 1; off < 64; off <<= 1) acc += __shfl_xor(acc, off);
  if (lane == 0) red[wid] = acc;
  __syncthreads();
  if (tid == 0) {
    float a = red[0];
    #pragma unroll
    for (int i = 1; i < 16; ++i) a += red[i];
    part[bid] = a;
  }
  gbar(cnt, gen);

  if (bid == 0) {
    if (tid < 256) sd[tid] = (double)part[tid];
    __syncthreads();
    for (int k = 128; k > 0; k >>= 1) {
      if (tid < k) sd[tid] += sd[tid + k];
      __syncthreads();
    }
    if (tid == 0) out[0] = (float)(sd[0] / (double)Bb);
  }
}

extern "C" void kernel_launch(void* const* d_in, const int* in_sizes, int n_in,
                              void* d_out, int out_size, void* d_ws, size_t ws_size,
                              hipStream_t stream) {
  (void)in_sizes; (void)n_in; (void)out_size; (void)ws_size;
  const float* p1 = (const float*)d_in[0];
  const float* p2 = (const float*)d_in[1];
  char* ws = (char*)d_ws;
  float4*   pk1   = (float4*)(ws + 0);          // 524288
  float4*   pk2   = (float4*)(ws + 524288);     // 524288
  float*    U     = (float*)(ws + 1048576);     // 131072
  float*    V     = (float*)(ws + 1179648);     // 131072
  unsigned* slots = (unsigned*)(ws + 1310720);  // 102400
  float*    part  = (float*)(ws + 1413120);     // 1024
  float4*   bbox  = (float4*)(ws + 1421312);    // 1024
  float4*   cbox  = (float4*)(ws + 1422336);    // 32768
  float*    cm    = (float*)(ws + 1455104);     // 4096
  unsigned* cnt   = (unsigned*)(ws + 1459200);
  unsigned* gen   = (unsigned*)(ws + 1459264);  // separate cacheline

  const int npts = Bb * Nn;
  pack_pts<<<(npts + BLOCK - 1) / BLOCK, BLOCK, 0, stream>>>(p1, pk1, npts);
  pack_pts<<<(npts + BLOCK - 1) / BLOCK, BLOCK, 0, stream>>>(p2, pk2, npts);
  init_bar<<<1, 1, 0, stream>>>(cnt, gen);
  bbox_k<<<32, BLOCK, 0, stream>>>(pk1, pk2, bbox);
  sort_k<<<32, BLOCK, 0, stream>>>(pk1, pk2, bbox, cbox);

  sink_all<<<PGRID, BLK, 0, stream>>>(pk1, pk2, U, V, slots, cbox, cm,
                                      part, (float*)d_out, cnt, gen);
}

// Round 15
// 9580.925 us; speedup vs baseline: 1.4858x; 1.4858x over previous
//
#include <hip/hip_runtime.h>
#include <math.h>

namespace {
constexpr int   Bb    = 16;
constexpr int   Nn    = 2048;
constexpr int   Mm    = 2048;
constexpr float EPSf  = 0.005f;
constexpr float TOLf  = 1e-3f;
constexpr int   MAXIT = 100;
constexpr float LN2f  = 0.69314718055994531f;
constexpr float L2Ef  = 1.44269504088896340f;  // log2(e)
constexpr float C2f   = 288.53900817779268f;   // log2(e)/EPS
constexpr int   BLOCK = 256;
constexpr int   PGRID = 1024;                  // 64 blocks/batch, 32 rows/block
constexpr int   BPB   = 64;                    // blocks per batch
constexpr int   NCH   = 64;                    // 32-pt chunks per batch
}

#define AGT __HIP_MEMORY_SCOPE_AGENT
__device__ __forceinline__ float ex2(float x) { return __builtin_amdgcn_exp2f(x); }
__device__ __forceinline__ float aload(const float* p) {
  return __hip_atomic_load(p, __ATOMIC_RELAXED, AGT);
}
__device__ __forceinline__ void astore(float* p, float v) {
  __hip_atomic_store(p, v, __ATOMIC_RELAXED, AGT);
}

__global__ __launch_bounds__(BLOCK) void pack_pts(const float* __restrict__ p,
                                                  float4* __restrict__ pk, int npts) {
  int i = blockIdx.x * BLOCK + threadIdx.x;
  if (i < npts) pk[i] = make_float4(p[3 * i], p[3 * i + 1], p[3 * i + 2], 0.0f);
}

__global__ __launch_bounds__(BLOCK) void init_bar(unsigned* bar) {
  for (int i = threadIdx.x; i < 544; i += BLOCK) bar[i] = 0u;
}

__global__ __launch_bounds__(BLOCK) void bbox_k(const float4* __restrict__ pk1,
                                                const float4* __restrict__ pk2,
                                                float4* __restrict__ bbox) {
  __shared__ float4 smin[BLOCK], smax[BLOCK];
  const int cb = blockIdx.x;
  const float4* p = (cb < 16 ? pk1 : pk2) + (cb & 15) * Nn;
  float4 mn = make_float4(3e38f, 3e38f, 3e38f, 0), mx = make_float4(-3e38f, -3e38f, -3e38f, 0);
  for (int i = threadIdx.x; i < Nn; i += BLOCK) {
    float4 v = p[i];
    mn.x = fminf(mn.x, v.x); mn.y = fminf(mn.y, v.y); mn.z = fminf(mn.z, v.z);
    mx.x = fmaxf(mx.x, v.x); mx.y = fmaxf(mx.y, v.y); mx.z = fmaxf(mx.z, v.z);
  }
  smin[threadIdx.x] = mn; smax[threadIdx.x] = mx;
  __syncthreads();
  for (int k = BLOCK / 2; k > 0; k >>= 1) {
    if (threadIdx.x < k) {
      float4 a = smin[threadIdx.x], c = smin[threadIdx.x + k];
      smin[threadIdx.x] = make_float4(fminf(a.x, c.x), fminf(a.y, c.y), fminf(a.z, c.z), 0);
      float4 d = smax[threadIdx.x], e = smax[threadIdx.x + k];
      smax[threadIdx.x] = make_float4(fmaxf(d.x, e.x), fmaxf(d.y, e.y), fmaxf(d.z, e.z), 0);
    }
    __syncthreads();
  }
  if (threadIdx.x == 0) { bbox[cb * 2] = smin[0]; bbox[cb * 2 + 1] = smax[0]; }
}

__device__ __forceinline__ unsigned spread3(unsigned v) {
  v = (v * 0x00010001u) & 0xFF0000FFu;
  v = (v * 0x00000101u) & 0x0F00F00Fu;
  v = (v * 0x00000011u) & 0xC30C30C3u;
  v = (v * 0x00000005u) & 0x49249249u;
  return v;
}

// Morton-sort one (cloud,batch) in LDS; 64 chunk-AABBs of 32 points each.
// Sort quality affects pruning speed only, never correctness.
__global__ __launch_bounds__(BLOCK) void sort_k(float4* __restrict__ pk1,
                                                float4* __restrict__ pk2,
                                                const float4* __restrict__ bbox,
                                                float4* __restrict__ chunkbox) {
  __shared__ float4 pts[Nn];                    // 32 KB
  __shared__ unsigned key[Nn];                  // 8 KB
  const int cb = blockIdx.x, tid = threadIdx.x;
  float4* p = (cb < 16 ? pk1 : pk2) + (cb & 15) * Nn;
  float4 lo = bbox[cb * 2], hi = bbox[cb * 2 + 1];
  float sx = 127.0f / fmaxf(hi.x - lo.x, 1e-9f);
  float sy = 127.0f / fmaxf(hi.y - lo.y, 1e-9f);
  float sz = 127.0f / fmaxf(hi.z - lo.z, 1e-9f);
  for (int i = tid; i < Nn; i += BLOCK) {
    float4 v = p[i];
    pts[i] = v;
    unsigned qx = (unsigned)fminf(fmaxf((v.x - lo.x) * sx, 0.f), 127.f);
    unsigned qy = (unsigned)fminf(fmaxf((v.y - lo.y) * sy, 0.f), 127.f);
    unsigned qz = (unsigned)fminf(fmaxf((v.z - lo.z) * sz, 0.f), 127.f);
    unsigned m = spread3(qx) | (spread3(qy) << 1) | (spread3(qz) << 2);
    key[i] = (m << 11) | (unsigned)i;
  }
  __syncthreads();
  for (int k = 2; k <= Nn; k <<= 1)
    for (int j = k >> 1; j > 0; j >>= 1) {
      for (int t = tid; t < Nn / 2; t += BLOCK) {
        int i = ((t & ~(j - 1)) << 1) | (t & (j - 1));
        int ixj = i | j;
        bool up = ((i & k) == 0);
        unsigned a = key[i], bq = key[ixj];
        if ((a > bq) == up) { key[i] = bq; key[ixj] = a; }
      }
      __syncthreads();
    }
  float4 g[Nn / BLOCK];
  #pragma unroll
  for (int c = 0; c < Nn / BLOCK; ++c)
    g[c] = pts[key[tid + c * BLOCK] & 2047u];
  __syncthreads();
  #pragma unroll
  for (int c = 0; c < Nn / BLOCK; ++c) {
    pts[tid + c * BLOCK] = g[c];
    p[tid + c * BLOCK]   = g[c];
  }
  __syncthreads();
  const int lane = tid & 63, wid = tid >> 6;
  for (int c2 = wid; c2 < 32; c2 += 4) {        // wave: chunk pair (2*c2, 2*c2+1)
    int c = 2 * c2 + (lane >> 5);
    float4 v = pts[c * 32 + (lane & 31)];
    float mnx = v.x, mny = v.y, mnz = v.z, mxx = v.x, mxy = v.y, mxz = v.z;
    #pragma unroll
    for (int off = 1; off < 32; off <<= 1) {    // stays within each 32-half
      mnx = fminf(mnx, __shfl_xor(mnx, off)); mny = fminf(mny, __shfl_xor(mny, off));
      mnz = fminf(mnz, __shfl_xor(mnz, off)); mxx = fmaxf(mxx, __shfl_xor(mxx, off));
      mxy = fmaxf(mxy, __shfl_xor(mxy, off)); mxz = fmaxf(mxz, __shfl_xor(mxz, off));
    }
    if ((lane & 31) == 0) {
      chunkbox[(cb * NCH + c) * 2]     = make_float4(mnx, mny, mnz, 0);
      chunkbox[(cb * NCH + c) * 2 + 1] = make_float4(mxx, mxy, mxz, 0);
    }
  }
}

// Fence-free hierarchical grid barrier: 64 blocks -> batch counter -> 16
// leaders -> global counter; broadcast via per-batch gen. All ops are agent
// atomics (L3-coherent); release on arrival drains this block's data stores.
// No cache invalidation anywhere (the R13 killer).
__device__ __forceinline__ void gbar(unsigned* bar, int b, int tid) {
  __syncthreads();
  if (tid == 0) {
    unsigned* cntG = bar;
    unsigned* genG = bar + 16;
    unsigned* arrB = bar + 32 + b * 16;
    unsigned* genB = bar + 288 + b * 16;
    unsigned g = __hip_atomic_load(genB, __ATOMIC_RELAXED, AGT);
    unsigned a = __hip_atomic_fetch_add(arrB, 1u, __ATOMIC_RELEASE, AGT);
    if (a == (unsigned)(BPB - 1)) {
      __hip_atomic_store(arrB, 0u, __ATOMIC_RELAXED, AGT);
      unsigned gg = __hip_atomic_load(genG, __ATOMIC_RELAXED, AGT);
      unsigned ag = __hip_atomic_fetch_add(cntG, 1u, __ATOMIC_ACQ_REL, AGT);
      if (ag == 15u) {
        __hip_atomic_store(cntG, 0u, __ATOMIC_RELAXED, AGT);
        __hip_atomic_store(genG, gg + 1u, __ATOMIC_RELEASE, AGT);
      } else {
        while (__hip_atomic_load(genG, __ATOMIC_RELAXED, AGT) == gg)
          __builtin_amdgcn_s_sleep(2);
      }
      __hip_atomic_store(genB, g + 1u, __ATOMIC_RELEASE, AGT);
    } else {
      while (__hip_atomic_load(genB, __ATOMIC_RELAXED, AGT) == g)
        __builtin_amdgcn_s_sleep(4);
    }
  }
  __syncthreads();
}

// One half-pass: this block's 32 rows (8/wave), fixed-shift LSE.
// full=true (it=0): msk=~0 -> pair-walk over all 64 chunks == full scan;
// K = log2ab (pots are 0) so no online-max needed. Coords cached; pots via L3.
__device__ void half_pass(bool full,
    const float4* __restrict__ PRq, const float4* __restrict__ PC,
    const float* __restrict__ potC, float* __restrict__ potR,
    const float4* __restrict__ cboxC, const float* __restrict__ cmC,
    float* __restrict__ cmO, unsigned* slot,
    int sb, int lane, int wid, int tid, float thrAdd,
    float* red, float* redw) {
  const float log_ab = logf(1.0f / 2048.0f + 1e-8f);
  const float log2ab = log_ab * L2Ef;
  const float invC2  = 1.0f / C2f;
  const int base = sb * 32 + wid * 8;

  float qx[8], qy[8], qz[8], K[8], up[8], S[8];
  #pragma unroll
  for (int r = 0; r < 8; ++r) {
    float4 q = PRq[base + r];                   // cached, wave-uniform
    qx[r] = q.x; qy[r] = q.y; qz[r] = q.z;
    up[r] = aload(&potR[base + r]);
    K[r]  = fmaf(up[r], -C2f, log2ab);
    S[r]  = 0.0f;
  }

  unsigned long long msk = ~0ull;
  if (!full) {
    float4 clo = cboxC[lane * 2], chi = cboxC[lane * 2 + 1];
    float cmw = aload(&cmC[lane]) * C2f;
    unsigned long long m = 0;
    #pragma unroll
    for (int r = 0; r < 8; ++r) {
      float thr = (cmw - K[r] + thrAdd) * invC2;
      float ax = fmaxf(fmaxf(clo.x - qx[r], qx[r] - chi.x), 0.0f);
      float ay = fmaxf(fmaxf(clo.y - qy[r], qy[r] - chi.y), 0.0f);
      float az = fmaxf(fmaxf(clo.z - qz[r], qz[r] - chi.z), 0.0f);
      float d2low = fmaf(az, az, fmaf(ay, ay, ax * ax));
      bool keep = (thr > 0.0f) && (d2low <= thr * thr);
      m |= __ballot(keep);
    }
    msk = m;
  }

  while (msk) {                                 // two chunks per iteration
    int cA = __builtin_ctzll(msk); msk &= msk - 1;
    bool h2 = (msk != 0ull);
    int cB = cA;
    if (h2) { cB = __builtin_ctzll(msk); msk &= msk - 1; }
    int c = (lane < 32) ? cA : cB;
    int idx = c * 32 + (lane & 31);
    float4 f = PC[idx];                         // cached coords
    float w  = aload(&potC[idx]) * C2f;         // L3 (mutable)
    if (!h2 && lane >= 32) w = -3.0e38f;        // kill duplicate half
    #pragma unroll
    for (int r = 0; r < 8; ++r) {
      float dx = f.x - qx[r], dy = f.y - qy[r], dz = f.z - qz[r];
      float d2 = fmaf(dz, dz, fmaf(dy, dy, dx * dx));
      S[r] += ex2(fmaf(__builtin_amdgcn_sqrtf(d2), -C2f, w) - K[r]);
    }
  }

  float dmax = 0.0f, wmax = -3.0e38f;
  #pragma unroll
  for (int r = 0; r < 8; ++r) {
    float sv = S[r];
    #pragma unroll
    for (int off = 1; off < 64; off <<= 1) sv += __shfl_xor(sv, off);
    sv = fmaxf(sv, 1e-37f);
    float lse = (K[r] + __builtin_amdgcn_logf(sv)) * LN2f;  // v_log_f32 = log2
    float pnew = EPSf * (log_ab - lse);
    if (lane == 0) {
      dmax = fmaxf(dmax, fabsf(pnew - up[r]));
      astore(&potR[base + r], pnew);
      wmax = fmaxf(wmax, pnew);
    }
  }
  if (lane == 0) { red[wid] = dmax; redw[wid] = wmax; }
  __syncthreads();
  if (tid == 0) {
    float m = fmaxf(fmaxf(red[0], red[1]), fmaxf(red[2], red[3]));
    atomicMax(slot, __float_as_uint(m));        // device-scope atomic (m20)
    float w = fmaxf(fmaxf(redw[0], redw[1]), fmaxf(redw[2], redw[3]));
    astore(&cmO[sb], w);                        // block = chunk: single writer
  }
  __syncthreads();
}

__global__ __launch_bounds__(BLOCK, 6) void sink_all(
    const float4* __restrict__ pk1, const float4* __restrict__ pk2,
    float* __restrict__ Upot, float* __restrict__ Vpot,
    unsigned* __restrict__ slots, const float4* __restrict__ cbox,
    float* __restrict__ cm, float* __restrict__ part,
    float* __restrict__ out, unsigned* __restrict__ bar) {
  __shared__ float red[4], redw[4];
  __shared__ float convm;
  __shared__ double sd[BLOCK];
  const int bid = blockIdx.x, tid = threadIdx.x, lane = tid & 63, wid = tid >> 6;
  const int b = bid >> 6, sb = bid & 63;

  // prologue: zero potentials AND slots (R14 bug: poisoned 0xAA slots read as
  // negative floats -> "converged" after it=0 -> 3% error). Replay-safe.
  if (tid < 32) {
    astore(&Upot[b * Nn + sb * 32 + tid], 0.0f);
    astore(&Vpot[b * Nn + sb * 32 + tid], 0.0f);
  }
  for (int i = bid * BLOCK + tid; i < MAXIT * 16 * 16; i += PGRID * BLOCK)
    __hip_atomic_store(&slots[i], 0u, __ATOMIC_RELAXED, AGT);
  gbar(bar, b, tid);

  const float4* PK1 = pk1 + b * Nn;
  const float4* PK2 = pk2 + b * Nn;
  float* Ub = Upot + b * Nn;
  float* Vb = Vpot + b * Nn;
  const float4* cbox1 = cbox + b * NCH * 2;
  const float4* cbox2 = cbox + (16 + b) * NCH * 2;
  float* cm1 = cm + b * NCH;
  float* cm2 = cm + 1024 + b * NCH;

  for (int it = 0; it < MAXIT; ++it) {
    float thr = (it < 4) ? 120.0f : 80.0f;
    bool full = (it == 0);
    // u-update: rows pk1 vs cols (pk2, V); writes U, cm1, slot uv=0
    half_pass(full, PK1, PK2, Vb, Ub, cbox2, cm2, cm1,
              slots + (it * 16 + b) * 16 + 0, sb, lane, wid, tid, thr, red, redw);
    gbar(bar, b, tid);
    // v-update: rows pk2 vs cols (pk1, U_new); writes V, cm2, slot uv=1
    half_pass(full, PK2, PK1, Ub, Vb, cbox1, cm1, cm2,
              slots + (it * 16 + b) * 16 + 1, sb, lane, wid, tid, thr, red, redw);
    gbar(bar, b, tid);
    // uniform convergence check on THIS iteration's slots (reference: done |= conv)
    if (tid < 32) {
      float v = __uint_as_float(__hip_atomic_load(
          (const unsigned*)&slots[(it * 16 + (tid >> 1)) * 16 + (tid & 1)],
          __ATOMIC_RELAXED, AGT));
      #pragma unroll
      for (int off = 16; off >= 1; off >>= 1) v = fmaxf(v, __shfl_xor(v, off));
      if (tid == 0) convm = v;
    }
    __syncthreads();
    if (convm < TOLf) break;                    // uniform across all blocks
  }

  // final: sum exp((u+v-dist)/eps)*dist over this block's 32 rows (full scan)
  {
    const int base = sb * 32 + wid * 8;
    float qx[8], qy[8], qz[8], uc[8];
    #pragma unroll
    for (int r = 0; r < 8; ++r) {
      float4 q = PK1[base + r];
      qx[r] = q.x; qy[r] = q.y; qz[r] = q.z;
      uc[r] = aload(&Ub[base + r]) * C2f;
    }
    float acc = 0.0f;
    for (int t = 0; t < 32; ++t) {
      int idx = t * 64 + lane;
      float4 f = PK2[idx];
      float w  = aload(&Vb[idx]) * C2f;
      #pragma unroll
      for (int r = 0; r < 8; ++r) {
        float dx = f.x - qx[r], dy = f.y - qy[r], dz = f.z - qz[r];
        float d2 = fmaf(dz, dz, fmaf(dy, dy, dx * dx));
        float td = __builtin_amdgcn_sqrtf(d2);
        acc = fmaf(ex2(fmaf(td, -C2f, w) + uc[r]), td, acc);
      }
    }
    #pragma unroll
    for (int off = 1; off < 64; off <<= 1) acc += __shfl_xor(acc, off);
    if (lane == 0) red[wid] = acc;
    __syncthreads();
    if (tid == 0)
      astore(&part[bid], (red[0] + red[1]) + (red[2] + red[3]));
  }
  gbar(bar, b, tid);

  if (bid == 0) {
    double s = 0.0;
    for (int i = tid; i < PGRID; i += BLOCK) s += (double)aload(&part[i]);
    sd[tid] = s;
    __syncthreads();
    for (int k = BLOCK / 2; k > 0; k >>= 1) {
      if (tid < k) sd[tid] += sd[tid + k];
      __syncthreads();
    }
    if (tid == 0) out[0] = (float)(sd[0] / (double)Bb);
  }
}

extern "C" void kernel_launch(void* const* d_in, const int* in_sizes, int n_in,
                              void* d_out, int out_size, void* d_ws, size_t ws_size,
                              hipStream_t stream) {
  (void)in_sizes; (void)n_in; (void)out_size; (void)ws_size;
  const float* p1 = (const float*)d_in[0];
  const float* p2 = (const float*)d_in[1];
  char* ws = (char*)d_ws;
  float4*   pk1   = (float4*)(ws + 0);          // 524288
  float4*   pk2   = (float4*)(ws + 524288);     // 524288
  float*    U     = (float*)(ws + 1048576);     // 131072
  float*    V     = (float*)(ws + 1179648);     // 131072
  unsigned* slots = (unsigned*)(ws + 1310720);  // 100*16*16*4 = 102400
  float*    part  = (float*)(ws + 1413120);     // 4096
  float4*   bbox  = (float4*)(ws + 1417216);    // 1024
  float4*   cbox  = (float4*)(ws + 1418240);    // 2*16*64*2*16 = 65536
  float*    cm    = (float*)(ws + 1483776);     // 8192
  unsigned* bar   = (unsigned*)(ws + 1491968);  // 4096

  const int npts = Bb * Nn;
  pack_pts<<<(npts + BLOCK - 1) / BLOCK, BLOCK, 0, stream>>>(p1, pk1, npts);
  pack_pts<<<(npts + BLOCK - 1) / BLOCK, BLOCK, 0, stream>>>(p2, pk2, npts);
  bbox_k<<<32, BLOCK, 0, stream>>>(pk1, pk2, bbox);
  sort_k<<<32, BLOCK, 0, stream>>>(pk1, pk2, bbox, cbox);
  init_bar<<<1, BLOCK, 0, stream>>>(bar);

  sink_all<<<PGRID, BLOCK, 0, stream>>>(pk1, pk2, U, V, slots, cbox, cm,
                                        part, (float*)d_out, bar);
}